// Round 1
// baseline (1221.017 us; speedup 1.0000x reference)
//
#include <hip/hip_runtime.h>
#include <hip/hip_bf16.h>
#include <math.h>

// Problem constants (reference: B,T,D,U = 32,4096,512,512)
#define B_ 32
#define T_ 4096
#define D_ 512
#define U_ 512

// ---------------------------------------------------------------------------
// K1: q_proj[b][u] = sum_k query[b][k]*W1[k][u] + b1[u] + b2[u]
// (b2 folded in here; bv dropped entirely since softmax is shift-invariant)
// grid: 32 blocks, 256 threads
// ---------------------------------------------------------------------------
__global__ __launch_bounds__(256) void qproj_kernel(
    const float* __restrict__ query, const float* __restrict__ W1,
    const float* __restrict__ b1, const float* __restrict__ b2,
    float* __restrict__ qp) {
  const int b = blockIdx.x;
  const int tid = threadIdx.x;
  __shared__ float qs[D_];
  qs[tid]       = query[b * D_ + tid];
  qs[tid + 256] = query[b * D_ + tid + 256];
  __syncthreads();
  const int u0 = tid * 2;
  float ax = 0.f, ay = 0.f;
#pragma unroll 8
  for (int k = 0; k < D_; ++k) {
    const float q = qs[k];
    const float2 w = *(const float2*)&W1[(size_t)k * U_ + u0];
    ax += q * w.x;
    ay += q * w.y;
  }
  qp[b * U_ + u0]     = ax + b1[u0]     + b2[u0];
  qp[b * U_ + u0 + 1] = ay + b1[u0 + 1] + b2[u0 + 1];
}

// ---------------------------------------------------------------------------
// K2 (the heavy one): for each (b,t):
//   score[b][t] = sum_u tanh( qp[b][u] + sum_k values[b][t][k]*W2[k][u] ) * V[u]
// Tiled GEMM fused with tanh/V-dot epilogue. 68.7 GFLOP fp32 on vector ALU.
// Block: 256 threads, one b, 64 t-rows. u processed in 4 chunks of 128.
// Per-thread register tile: 4 t x 8 u = 32 acc. 32 FMA per k-step.
// grid: (T/64, B) = (64, 32)
// ---------------------------------------------------------------------------
#define BM 64
#define BK 32
#define VSP 36  // values LDS row stride: 36 floats -> 144B (16B aligned rows,
                // bank = (4t+k)%32 -> conflict-free for t = ty+16i reads)

__global__ __launch_bounds__(256) void scores_kernel(
    const float* __restrict__ values, const float* __restrict__ W2,
    const float* __restrict__ qp, const float* __restrict__ V,
    float* __restrict__ scores) {
  const int b = blockIdx.y;
  const int t0 = blockIdx.x * BM;
  const int tid = threadIdx.x;
  const int tx = tid & 15;   // u direction (16)
  const int ty = tid >> 4;   // t direction (16)

  __shared__ float vs[BM][VSP];     // 64*36*4 = 9216 B
  __shared__ float w2s[BK][128];    // 32*128*4 = 16384 B

  const float* vbase = values + ((size_t)b * T_ + t0) * D_;

  float sp[4] = {0.f, 0.f, 0.f, 0.f};  // per-thread partial scores (4 t's)

  for (int uc = 0; uc < 4; ++uc) {
    float acc[4][8];
#pragma unroll
    for (int i = 0; i < 4; ++i)
#pragma unroll
      for (int j = 0; j < 8; ++j) acc[i][j] = 0.f;

    for (int k0 = 0; k0 < D_; k0 += BK) {
      __syncthreads();
      // stage values tile: 64 rows x 32 k = 512 float4, 2 per thread
#pragma unroll
      for (int p = 0; p < 2; ++p) {
        const int id = tid + 256 * p;
        const int r = id >> 3, c = id & 7;
        const float4 v4 = *(const float4*)&vbase[(size_t)r * D_ + k0 + c * 4];
        *(float4*)&vs[r][c * 4] = v4;   // 144B row stride keeps 16B alignment
      }
      // stage W2 chunk: 32 k x 128 u = 1024 float4, 4 per thread (coalesced)
#pragma unroll
      for (int p = 0; p < 4; ++p) {
        const int id = tid + 256 * p;
        const int kk = id >> 5, uu = id & 31;
        const float4 w4 =
            *(const float4*)&W2[(size_t)(k0 + kk) * U_ + uc * 128 + uu * 4];
        *(float4*)&w2s[kk][uu * 4] = w4;
      }
      __syncthreads();

#pragma unroll
      for (int k = 0; k < BK; ++k) {
        float a[4];
#pragma unroll
        for (int i = 0; i < 4; ++i) a[i] = vs[ty + 16 * i][k];
        const float4 w0 = *(const float4*)&w2s[k][tx * 4];        // 2-way: free
        const float4 w1 = *(const float4*)&w2s[k][64 + tx * 4];
#pragma unroll
        for (int i = 0; i < 4; ++i) {
          acc[i][0] += a[i] * w0.x;
          acc[i][1] += a[i] * w0.y;
          acc[i][2] += a[i] * w0.z;
          acc[i][3] += a[i] * w0.w;
          acc[i][4] += a[i] * w1.x;
          acc[i][5] += a[i] * w1.y;
          acc[i][6] += a[i] * w1.z;
          acc[i][7] += a[i] * w1.w;
        }
      }
    }

    // epilogue for this u-chunk: sp[i] += sum_j tanh(acc + qp[u]) * V[u]
    const float* qpb = qp + b * U_ + uc * 128;
    const float* Vb = V + uc * 128;
    float qv[8], vv[8];
#pragma unroll
    for (int j = 0; j < 8; ++j) {
      const int u = (j < 4) ? (tx * 4 + j) : (64 + tx * 4 + (j - 4));
      qv[j] = qpb[u];
      vv[j] = Vb[u];
    }
#pragma unroll
    for (int i = 0; i < 4; ++i) {
      float s = 0.f;
#pragma unroll
      for (int j = 0; j < 8; ++j) s += tanhf(acc[i][j] + qv[j]) * vv[j];
      sp[i] += s;
    }
  }

  // reduce across the 16 tx lanes (contiguous lanes within the wave)
#pragma unroll
  for (int i = 0; i < 4; ++i) {
    float s = sp[i];
    s += __shfl_xor(s, 1);
    s += __shfl_xor(s, 2);
    s += __shfl_xor(s, 4);
    s += __shfl_xor(s, 8);
    if (tx == 0) scores[(size_t)b * T_ + t0 + ty + 16 * i] = s;
  }
}

// ---------------------------------------------------------------------------
// K3: softmax over T per batch, in place (scores -> attn). grid: 32 blocks.
// ---------------------------------------------------------------------------
__global__ __launch_bounds__(256) void softmax_kernel(float* __restrict__ sc) {
  const int b = blockIdx.x;
  const int tid = threadIdx.x;
  __shared__ float red[256];
  float* s = sc + (size_t)b * T_;
  float v[16];
  float lmax = -1e30f;
#pragma unroll
  for (int i = 0; i < 16; ++i) {
    v[i] = s[tid + 256 * i];
    lmax = fmaxf(lmax, v[i]);
  }
  red[tid] = lmax;
  __syncthreads();
  for (int off = 128; off > 0; off >>= 1) {
    if (tid < off) red[tid] = fmaxf(red[tid], red[tid + off]);
    __syncthreads();
  }
  const float m = red[0];
  __syncthreads();
  float lsum = 0.f;
#pragma unroll
  for (int i = 0; i < 16; ++i) {
    v[i] = expf(v[i] - m);
    lsum += v[i];
  }
  red[tid] = lsum;
  __syncthreads();
  for (int off = 128; off > 0; off >>= 1) {
    if (tid < off) red[tid] += red[tid + off];
    __syncthreads();
  }
  const float inv = 1.0f / red[0];
#pragma unroll
  for (int i = 0; i < 16; ++i) s[tid + 256 * i] = v[i] * inv;
}

// ---------------------------------------------------------------------------
// K4: context[b][d] = sum_t attn[b][t] * values[b][t][d]
// grid: (B, 8) — each block does 512 t's, 256 threads x float2 over D=512.
// fp32 atomicAdd into zeroed d_out (8 adds per element).
// ---------------------------------------------------------------------------
__global__ __launch_bounds__(256) void context_kernel(
    const float* __restrict__ values, const float* __restrict__ attn,
    float* __restrict__ out) {
  const int b = blockIdx.x;
  const int t0 = blockIdx.y * 512;
  const int tid = threadIdx.x;
  __shared__ float as[512];
  as[tid]       = attn[(size_t)b * T_ + t0 + tid];
  as[tid + 256] = attn[(size_t)b * T_ + t0 + tid + 256];
  __syncthreads();
  const float* vb = values + ((size_t)b * T_ + t0) * D_;
  const int d = tid * 2;
  float ax = 0.f, ay = 0.f;
#pragma unroll 4
  for (int t = 0; t < 512; ++t) {
    const float a = as[t];
    const float2 v = *(const float2*)&vb[(size_t)t * D_ + d];
    ax += a * v.x;
    ay += a * v.y;
  }
  atomicAdd(&out[b * D_ + d], ax);
  atomicAdd(&out[b * D_ + d + 1], ay);
}

// ---------------------------------------------------------------------------
extern "C" void kernel_launch(void* const* d_in, const int* in_sizes, int n_in,
                              void* d_out, int out_size, void* d_ws,
                              size_t ws_size, hipStream_t stream) {
  const float* query = (const float*)d_in[0];  // [B, D]
  const float* values = (const float*)d_in[1]; // [B, T, D]
  const float* W1 = (const float*)d_in[2];     // [D, U]
  const float* b1 = (const float*)d_in[3];     // [U]
  const float* W2 = (const float*)d_in[4];     // [D, U]
  const float* b2 = (const float*)d_in[5];     // [U]
  const float* V = (const float*)d_in[6];      // [U, 1]
  // d_in[7] = bv : dropped (softmax shift-invariant)

  float* qp = (float*)d_ws;                       // B*U = 16384 floats
  float* scores = qp + (size_t)B_ * U_;           // B*T = 131072 floats (attn in-place)
  float* out = (float*)d_out;                     // [B, D]

  hipMemsetAsync(d_out, 0, (size_t)B_ * D_ * sizeof(float), stream);

  qproj_kernel<<<B_, 256, 0, stream>>>(query, W1, b1, b2, qp);
  scores_kernel<<<dim3(T_ / BM, B_), 256, 0, stream>>>(values, W2, qp, V,
                                                       scores);
  softmax_kernel<<<B_, 256, 0, stream>>>(scores);
  context_kernel<<<dim3(B_, 8), 256, 0, stream>>>(values, scores, out);
}

// Round 2
// 599.592 us; speedup vs baseline: 2.0364x; 2.0364x over previous
//
#include <hip/hip_runtime.h>
#include <hip/hip_bf16.h>
#include <math.h>

#define B_ 32
#define T_ 4096
#define D_ 512
#define U_ 512

typedef __bf16 bf16x8 __attribute__((ext_vector_type(8)));
typedef float floatx4 __attribute__((ext_vector_type(4)));
typedef unsigned short ushortx8 __attribute__((ext_vector_type(8)));

// exact RNE float -> bf16 (inputs are normal floats; no NaN handling needed)
static __device__ __forceinline__ unsigned short f2bf(float f) {
  unsigned int u = __float_as_uint(f);
  unsigned int r = (u + 0x7fffu + ((u >> 16) & 1u)) >> 16;
  return (unsigned short)r;
}

// ---------------------------------------------------------------------------
// P0: W2T[u][k] = bf16(W2[k][u])  (512x512, LDS-tiled transpose)
// grid (16,16), block (32,8)
// ---------------------------------------------------------------------------
__global__ __launch_bounds__(256) void prep_w2t(
    const float* __restrict__ W2, unsigned short* __restrict__ W2T) {
  __shared__ float tile[32][33];
  const int bx = blockIdx.x * 32;  // k base
  const int by = blockIdx.y * 32;  // u base
  const int x = threadIdx.x;
#pragma unroll
  for (int y = threadIdx.y; y < 32; y += 8)
    tile[y][x] = W2[(size_t)(bx + y) * U_ + by + x];
  __syncthreads();
#pragma unroll
  for (int y = threadIdx.y; y < 32; y += 8)
    W2T[(size_t)(by + y) * D_ + bx + x] = f2bf(tile[x][y]);
}

// ---------------------------------------------------------------------------
// K1: q_proj[b][u] = query[b]@W1[:,u] + b1[u] + b2[u]   (fp32, tiny)
// ---------------------------------------------------------------------------
__global__ __launch_bounds__(256) void qproj_kernel(
    const float* __restrict__ query, const float* __restrict__ W1,
    const float* __restrict__ b1, const float* __restrict__ b2,
    float* __restrict__ qp) {
  const int b = blockIdx.x;
  const int tid = threadIdx.x;
  __shared__ float qs[D_];
  qs[tid] = query[b * D_ + tid];
  qs[tid + 256] = query[b * D_ + tid + 256];
  __syncthreads();
  const int u0 = tid * 2;
  float ax = 0.f, ay = 0.f;
#pragma unroll 8
  for (int k = 0; k < D_; ++k) {
    const float q = qs[k];
    const float2 w = *(const float2*)&W1[(size_t)k * U_ + u0];
    ax += q * w.x;
    ay += q * w.y;
  }
  qp[b * U_ + u0] = ax + b1[u0] + b2[u0];
  qp[b * U_ + u0 + 1] = ay + b1[u0 + 1] + b2[u0 + 1];
}

// ---------------------------------------------------------------------------
// K2: bf16-MFMA scores GEMM, fused tanh/V epilogue.
// Block = 256 thr (4 waves), tile 128t x 128u, BK=32, 16x16x32 bf16 MFMA.
// grid (T/128, B, U/128) = (32, 32, 4); partial row-sums atomicAdd -> scores.
// ---------------------------------------------------------------------------
__global__ __launch_bounds__(256) void scores_mfma(
    const float* __restrict__ values, const unsigned short* __restrict__ W2T,
    const float* __restrict__ qp, const float* __restrict__ V,
    float* __restrict__ scores) {
  const int b = blockIdx.y;
  const int t0 = blockIdx.x * 128;
  const int u0 = blockIdx.z * 128;
  const int tid = threadIdx.x;

  __shared__ __align__(16) unsigned short As[128 * 32];  // [t][k] 8 KB
  __shared__ __align__(16) unsigned short Bs[128 * 32];  // [u][k] 8 KB

  const int w = tid >> 6;
  const int lane = tid & 63;
  const int mo = (w & 1) * 64;   // wave t-offset in tile
  const int no = (w >> 1) * 64;  // wave u-offset in tile
  const int lr = lane & 15;
  const int koff = (lane >> 4) * 8;

  const float* vbase = values + ((size_t)b * T_ + t0) * D_;

  floatx4 acc[4][4];
#pragma unroll
  for (int i = 0; i < 4; ++i)
#pragma unroll
    for (int j = 0; j < 4; ++j) acc[i][j] = (floatx4)0.f;

  for (int k0 = 0; k0 < D_; k0 += 32) {
    __syncthreads();
    // stage A: values fp32 -> bf16, 128 rows x 32 k
#pragma unroll
    for (int p = 0; p < 2; ++p) {
      const int id = tid + 256 * p;
      const int r = id >> 2, c = (id & 3) * 8;
      const float4 f0 = *(const float4*)&vbase[(size_t)r * D_ + k0 + c];
      const float4 f1 = *(const float4*)&vbase[(size_t)r * D_ + k0 + c + 4];
      ushortx8 pk;
      pk[0] = f2bf(f0.x); pk[1] = f2bf(f0.y);
      pk[2] = f2bf(f0.z); pk[3] = f2bf(f0.w);
      pk[4] = f2bf(f1.x); pk[5] = f2bf(f1.y);
      pk[6] = f2bf(f1.z); pk[7] = f2bf(f1.w);
      *(ushortx8*)&As[r * 32 + c] = pk;
    }
    // stage B: W2T bf16 rows (k-contiguous), 128 rows x 32 k
#pragma unroll
    for (int p = 0; p < 2; ++p) {
      const int id = tid + 256 * p;
      const int r = id >> 2, c = (id & 3) * 8;
      *(ushortx8*)&Bs[r * 32 + c] =
          *(const ushortx8*)&W2T[(size_t)(u0 + r) * D_ + k0 + c];
    }
    __syncthreads();

    bf16x8 af[4], bf[4];
#pragma unroll
    for (int i = 0; i < 4; ++i)
      af[i] = __builtin_bit_cast(
          bf16x8, *(ushortx8*)&As[(mo + i * 16 + lr) * 32 + koff]);
#pragma unroll
    for (int j = 0; j < 4; ++j)
      bf[j] = __builtin_bit_cast(
          bf16x8, *(ushortx8*)&Bs[(no + j * 16 + lr) * 32 + koff]);
#pragma unroll
    for (int i = 0; i < 4; ++i)
#pragma unroll
      for (int j = 0; j < 4; ++j)
        acc[i][j] = __builtin_amdgcn_mfma_f32_16x16x32_bf16(af[i], bf[j],
                                                            acc[i][j], 0, 0, 0);
  }

  // epilogue: score_part[t] = sum_n tanh(acc + qp[u]) * V[u]
  // C/D layout: n = lr (lane&15), m = (lane>>4)*4 + reg
  const float* qpb = qp + b * U_ + u0;
  float qv[4], vv[4];
#pragma unroll
  for (int j = 0; j < 4; ++j) {
    qv[j] = qpb[no + j * 16 + lr];
    vv[j] = V[u0 + no + j * 16 + lr];
  }
#pragma unroll
  for (int i = 0; i < 4; ++i) {
#pragma unroll
    for (int r = 0; r < 4; ++r) {
      float s = 0.f;
#pragma unroll
      for (int j = 0; j < 4; ++j) s += tanhf(acc[i][j][r] + qv[j]) * vv[j];
      s += __shfl_xor(s, 1);
      s += __shfl_xor(s, 2);
      s += __shfl_xor(s, 4);
      s += __shfl_xor(s, 8);
      if (lr == 0) {
        const int m = mo + i * 16 + (lane >> 4) * 4 + r;
        atomicAdd(&scores[(size_t)b * T_ + t0 + m], s);
      }
    }
  }
}

// ---------------------------------------------------------------------------
// K3: softmax over T per batch, in place. grid: 32 blocks x 256 thr.
// ---------------------------------------------------------------------------
__global__ __launch_bounds__(256) void softmax_kernel(float* __restrict__ sc) {
  const int b = blockIdx.x;
  const int tid = threadIdx.x;
  __shared__ float red[256];
  float* s = sc + (size_t)b * T_;
  float v[16];
  float lmax = -1e30f;
#pragma unroll
  for (int i = 0; i < 16; ++i) {
    v[i] = s[tid + 256 * i];
    lmax = fmaxf(lmax, v[i]);
  }
  red[tid] = lmax;
  __syncthreads();
  for (int off = 128; off > 0; off >>= 1) {
    if (tid < off) red[tid] = fmaxf(red[tid], red[tid + off]);
    __syncthreads();
  }
  const float m = red[0];
  __syncthreads();
  float lsum = 0.f;
#pragma unroll
  for (int i = 0; i < 16; ++i) {
    v[i] = expf(v[i] - m);
    lsum += v[i];
  }
  red[tid] = lsum;
  __syncthreads();
  for (int off = 128; off > 0; off >>= 1) {
    if (tid < off) red[tid] += red[tid + off];
    __syncthreads();
  }
  const float inv = 1.0f / red[0];
#pragma unroll
  for (int i = 0; i < 16; ++i) s[tid + 256 * i] = v[i] * inv;
}

// ---------------------------------------------------------------------------
// K4: context[b][d] = sum_t attn[b][t]*values[b][t][d]
// grid (B, 32): 128 t-rows per block; 256 thr = 2 rows x 128 float4 lanes.
// ---------------------------------------------------------------------------
__global__ __launch_bounds__(256) void context_kernel(
    const float* __restrict__ values, const float* __restrict__ attn,
    float* __restrict__ out) {
  const int b = blockIdx.x;
  const int t0 = blockIdx.y * 128;
  const int tid = threadIdx.x;
  const int tx = tid & 127;
  const int ty = tid >> 7;
  __shared__ float as[128];
  __shared__ float4 red[128];
  if (tid < 128) as[tid] = attn[(size_t)b * T_ + t0 + tid];
  __syncthreads();
  const float* vb = values + ((size_t)b * T_ + t0) * D_;
  float ax = 0.f, ay = 0.f, az = 0.f, aw = 0.f;
#pragma unroll 4
  for (int t = ty; t < 128; t += 2) {
    const float a = as[t];
    const float4 v = *(const float4*)&vb[(size_t)t * D_ + tx * 4];
    ax += a * v.x;
    ay += a * v.y;
    az += a * v.z;
    aw += a * v.w;
  }
  if (ty == 1) red[tx] = make_float4(ax, ay, az, aw);
  __syncthreads();
  if (ty == 0) {
    const float4 o = red[tx];
    const int d = tx * 4;
    atomicAdd(&out[b * D_ + d],     ax + o.x);
    atomicAdd(&out[b * D_ + d + 1], ay + o.y);
    atomicAdd(&out[b * D_ + d + 2], az + o.z);
    atomicAdd(&out[b * D_ + d + 3], aw + o.w);
  }
}

// ---------------------------------------------------------------------------
extern "C" void kernel_launch(void* const* d_in, const int* in_sizes, int n_in,
                              void* d_out, int out_size, void* d_ws,
                              size_t ws_size, hipStream_t stream) {
  const float* query = (const float*)d_in[0];
  const float* values = (const float*)d_in[1];
  const float* W1 = (const float*)d_in[2];
  const float* b1 = (const float*)d_in[3];
  const float* W2 = (const float*)d_in[4];
  const float* b2 = (const float*)d_in[5];
  const float* V = (const float*)d_in[6];
  // d_in[7] = bv : dropped (softmax shift-invariant)

  // ws layout: qp (64 KB) | scores (512 KB) | W2T bf16 (512 KB)
  float* qp = (float*)d_ws;
  float* scores = qp + (size_t)B_ * U_;
  unsigned short* W2T = (unsigned short*)(scores + (size_t)B_ * T_);
  float* out = (float*)d_out;

  hipMemsetAsync(scores, 0, (size_t)B_ * T_ * sizeof(float), stream);
  hipMemsetAsync(d_out, 0, (size_t)B_ * D_ * sizeof(float), stream);

  prep_w2t<<<dim3(16, 16), dim3(32, 8), 0, stream>>>(W2, W2T);
  qproj_kernel<<<B_, 256, 0, stream>>>(query, W1, b1, b2, qp);
  scores_mfma<<<dim3(T_ / 128, B_, U_ / 128), 256, 0, stream>>>(values, W2T,
                                                                qp, V, scores);
  softmax_kernel<<<B_, 256, 0, stream>>>(scores);
  context_kernel<<<dim3(B_, 32), 256, 0, stream>>>(values, scores, out);
}

// Round 3
// 567.670 us; speedup vs baseline: 2.1509x; 1.0562x over previous
//
#include <hip/hip_runtime.h>
#include <hip/hip_bf16.h>
#include <math.h>

#define B_ 32
#define T_ 4096
#define D_ 512
#define U_ 512

typedef __bf16 bf16x8 __attribute__((ext_vector_type(8)));
typedef float floatx4 __attribute__((ext_vector_type(4)));
typedef unsigned short ushortx8 __attribute__((ext_vector_type(8)));

// exact RNE float -> bf16
static __device__ __forceinline__ unsigned short f2bf(float f) {
  unsigned int u = __float_as_uint(f);
  unsigned int r = (u + 0x7fffu + ((u >> 16) & 1u)) >> 16;
  return (unsigned short)r;
}

// fast tanh: 1 - 2/(exp2(2x*log2e)+1). v_exp_f32 + v_rcp_f32; exact at +/-inf.
static __device__ __forceinline__ float tanh_fast(float x) {
  float e = exp2f(x * 2.88539008178f);
  return 1.0f - 2.0f * __builtin_amdgcn_rcpf(1.0f + e);
}

// ---------------------------------------------------------------------------
// P0: W2T[u][k] = bf16(W2[k][u])  (512x512 LDS-tiled transpose)
// ---------------------------------------------------------------------------
__global__ __launch_bounds__(256) void prep_w2t(
    const float* __restrict__ W2, unsigned short* __restrict__ W2T) {
  __shared__ float tile[32][33];
  const int bx = blockIdx.x * 32;  // k base
  const int by = blockIdx.y * 32;  // u base
  const int x = threadIdx.x;
#pragma unroll
  for (int y = threadIdx.y; y < 32; y += 8)
    tile[y][x] = W2[(size_t)(bx + y) * U_ + by + x];
  __syncthreads();
#pragma unroll
  for (int y = threadIdx.y; y < 32; y += 8)
    W2T[(size_t)(by + y) * D_ + bx + x] = f2bf(tile[x][y]);
}

// ---------------------------------------------------------------------------
// K1: q_proj[b][u] = query[b]@W1[:,u] + b1[u] + b2[u]   (fp32, tiny)
// ---------------------------------------------------------------------------
__global__ __launch_bounds__(256) void qproj_kernel(
    const float* __restrict__ query, const float* __restrict__ W1,
    const float* __restrict__ b1, const float* __restrict__ b2,
    float* __restrict__ qp) {
  const int b = blockIdx.x;
  const int tid = threadIdx.x;
  __shared__ float qs[D_];
  qs[tid] = query[b * D_ + tid];
  qs[tid + 256] = query[b * D_ + tid + 256];
  __syncthreads();
  const int u0 = tid * 2;
  float ax = 0.f, ay = 0.f;
#pragma unroll 8
  for (int k = 0; k < D_; ++k) {
    const float q = qs[k];
    const float2 w = *(const float2*)&W1[(size_t)k * U_ + u0];
    ax += q * w.x;
    ay += q * w.y;
  }
  qp[b * U_ + u0] = ax + b1[u0] + b2[u0];
  qp[b * U_ + u0 + 1] = ay + b1[u0 + 1] + b2[u0 + 1];
}

// ---------------------------------------------------------------------------
// K2: scores. Block = 64 t x 512 u (full U -> no atomics). 4 waves split U.
// A (values, fp32->bf16) staged via LDS, chunk-major [4][66][8] (conflict-free
// b128 writes+reads). B fragments read DIRECT from L2-resident W2T (16B/lane,
// 64B-aligned segments) -- no B LDS round-trip. grid (T/64, B) = (64, 32).
// values fetched exactly once (268 MB).
// ---------------------------------------------------------------------------
__global__ __launch_bounds__(256, 2) void scores_mfma(
    const float* __restrict__ values, const unsigned short* __restrict__ W2T,
    const float* __restrict__ qp, const float* __restrict__ V,
    float* __restrict__ scores) {
  const int b = blockIdx.y;
  const int t0 = blockIdx.x * 64;
  const int tid = threadIdx.x;
  const int w = tid >> 6;
  const int lane = tid & 63;
  const int lr = lane & 15;          // fragment row within 16
  const int kc = lane >> 4;          // k-chunk 0..3 (8 shorts each)
  const int no = w * 128;            // wave's u-offset

  // As: chunk-major, chunk stride 66 rows * 8 shorts = 528 (1056 B ≡ 32 mod 128)
  __shared__ __align__(16) unsigned short As[4 * 528];  // 4224 B
  __shared__ float red[4][64];                          // cross-wave reduce

  const float* vbase = values + ((size_t)b * T_ + t0) * D_;
  const int arow = tid >> 2;         // staging: row 0..63
  const int achk = tid & 3;          // staging: k-chunk 0..3

  floatx4 acc[4][8];
#pragma unroll
  for (int i = 0; i < 4; ++i)
#pragma unroll
    for (int j = 0; j < 8; ++j) acc[i][j] = (floatx4)0.f;

  for (int k0 = 0; k0 < D_; k0 += 32) {
    __syncthreads();
    // stage A: 64 rows x 32 k, one ushortx8 per thread; quad reads 128 B
    {
      const float4* vp = (const float4*)&vbase[(size_t)arow * D_ + k0 + achk * 8];
      const float4 f0 = vp[0];
      const float4 f1 = vp[1];
      ushortx8 pk;
      pk[0] = f2bf(f0.x); pk[1] = f2bf(f0.y);
      pk[2] = f2bf(f0.z); pk[3] = f2bf(f0.w);
      pk[4] = f2bf(f1.x); pk[5] = f2bf(f1.y);
      pk[6] = f2bf(f1.z); pk[7] = f2bf(f1.w);
      *(ushortx8*)&As[achk * 528 + arow * 8] = pk;
    }
    __syncthreads();

    // B fragments direct from W2T (L2): lane -> row (no+j*16+lr), k kc*8
    bf16x8 bfr[8];
#pragma unroll
    for (int j = 0; j < 8; ++j)
      bfr[j] = __builtin_bit_cast(
          bf16x8,
          *(const ushortx8*)&W2T[(size_t)(no + j * 16 + lr) * D_ + k0 + kc * 8]);

    bf16x8 af[4];
#pragma unroll
    for (int i = 0; i < 4; ++i)
      af[i] = __builtin_bit_cast(
          bf16x8, *(ushortx8*)&As[kc * 528 + (i * 16 + lr) * 8]);

#pragma unroll
    for (int i = 0; i < 4; ++i)
#pragma unroll
      for (int j = 0; j < 8; ++j)
        acc[i][j] = __builtin_amdgcn_mfma_f32_16x16x32_bf16(af[i], bfr[j],
                                                            acc[i][j], 0, 0, 0);
  }

  // epilogue: C/D layout n(u) = lr, m(t) = i*16 + (lane>>4)*4 + reg
  const float* qpb = qp + b * U_;
  float qv[8], vv[8];
#pragma unroll
  for (int j = 0; j < 8; ++j) {
    const int u = no + j * 16 + lr;
    qv[j] = qpb[u];
    vv[j] = V[u];
  }
  const int mrow = (lane >> 4) * 4;
#pragma unroll
  for (int i = 0; i < 4; ++i) {
#pragma unroll
    for (int r = 0; r < 4; ++r) {
      float s = 0.f;
#pragma unroll
      for (int j = 0; j < 8; ++j) s += tanh_fast(acc[i][j][r] + qv[j]) * vv[j];
      s += __shfl_xor(s, 1);
      s += __shfl_xor(s, 2);
      s += __shfl_xor(s, 4);
      s += __shfl_xor(s, 8);
      if (lr == 0) red[w][i * 16 + mrow + r] = s;
    }
  }
  __syncthreads();
  if (tid < 64)
    scores[(size_t)b * T_ + t0 + tid] =
        red[0][tid] + red[1][tid] + red[2][tid] + red[3][tid];
}

// ---------------------------------------------------------------------------
// K3: softmax over T per batch, in place. grid: 32 blocks x 256 thr.
// ---------------------------------------------------------------------------
__global__ __launch_bounds__(256) void softmax_kernel(float* __restrict__ sc) {
  const int b = blockIdx.x;
  const int tid = threadIdx.x;
  __shared__ float red[256];
  float* s = sc + (size_t)b * T_;
  float v[16];
  float lmax = -1e30f;
#pragma unroll
  for (int i = 0; i < 16; ++i) {
    v[i] = s[tid + 256 * i];
    lmax = fmaxf(lmax, v[i]);
  }
  red[tid] = lmax;
  __syncthreads();
  for (int off = 128; off > 0; off >>= 1) {
    if (tid < off) red[tid] = fmaxf(red[tid], red[tid + off]);
    __syncthreads();
  }
  const float m = red[0];
  __syncthreads();
  float lsum = 0.f;
#pragma unroll
  for (int i = 0; i < 16; ++i) {
    v[i] = expf(v[i] - m);
    lsum += v[i];
  }
  red[tid] = lsum;
  __syncthreads();
  for (int off = 128; off > 0; off >>= 1) {
    if (tid < off) red[tid] += red[tid + off];
    __syncthreads();
  }
  const float inv = 1.0f / red[0];
#pragma unroll
  for (int i = 0; i < 16; ++i) s[tid + 256 * i] = v[i] * inv;
}

// ---------------------------------------------------------------------------
// K4: context[b][d] = sum_t attn[b][t]*values[b][t][d]
// grid (B, 32): 128 t-rows per block; 256 thr = 2 rows x 128 float4 lanes.
// ---------------------------------------------------------------------------
__global__ __launch_bounds__(256) void context_kernel(
    const float* __restrict__ values, const float* __restrict__ attn,
    float* __restrict__ out) {
  const int b = blockIdx.x;
  const int t0 = blockIdx.y * 128;
  const int tid = threadIdx.x;
  const int tx = tid & 127;
  const int ty = tid >> 7;
  __shared__ float as[128];
  __shared__ float4 red[128];
  if (tid < 128) as[tid] = attn[(size_t)b * T_ + t0 + tid];
  __syncthreads();
  const float* vb = values + ((size_t)b * T_ + t0) * D_;
  float ax = 0.f, ay = 0.f, az = 0.f, aw = 0.f;
#pragma unroll 8
  for (int t = ty; t < 128; t += 2) {
    const float a = as[t];
    const float4 v = *(const float4*)&vb[(size_t)t * D_ + tx * 4];
    ax += a * v.x;
    ay += a * v.y;
    az += a * v.z;
    aw += a * v.w;
  }
  if (ty == 1) red[tx] = make_float4(ax, ay, az, aw);
  __syncthreads();
  if (ty == 0) {
    const float4 o = red[tx];
    const int d = tx * 4;
    atomicAdd(&out[b * D_ + d],     ax + o.x);
    atomicAdd(&out[b * D_ + d + 1], ay + o.y);
    atomicAdd(&out[b * D_ + d + 2], az + o.z);
    atomicAdd(&out[b * D_ + d + 3], aw + o.w);
  }
}

// ---------------------------------------------------------------------------
extern "C" void kernel_launch(void* const* d_in, const int* in_sizes, int n_in,
                              void* d_out, int out_size, void* d_ws,
                              size_t ws_size, hipStream_t stream) {
  const float* query = (const float*)d_in[0];
  const float* values = (const float*)d_in[1];
  const float* W1 = (const float*)d_in[2];
  const float* b1 = (const float*)d_in[3];
  const float* W2 = (const float*)d_in[4];
  const float* b2 = (const float*)d_in[5];
  const float* V = (const float*)d_in[6];
  // d_in[7] = bv : dropped (softmax shift-invariant)

  // ws layout: qp (64 KB) | scores (512 KB) | W2T bf16 (512 KB)
  float* qp = (float*)d_ws;
  float* scores = qp + (size_t)B_ * U_;
  unsigned short* W2T = (unsigned short*)(scores + (size_t)B_ * T_);
  float* out = (float*)d_out;

  hipMemsetAsync(d_out, 0, (size_t)B_ * D_ * sizeof(float), stream);

  prep_w2t<<<dim3(16, 16), dim3(32, 8), 0, stream>>>(W2, W2T);
  qproj_kernel<<<B_, 256, 0, stream>>>(query, W1, b1, b2, qp);
  scores_mfma<<<dim3(T_ / 64, B_), 256, 0, stream>>>(values, W2T, qp, V,
                                                     scores);
  softmax_kernel<<<B_, 256, 0, stream>>>(scores);
  context_kernel<<<dim3(B_, 32), 256, 0, stream>>>(values, scores, out);
}

// Round 5
// 519.255 us; speedup vs baseline: 2.3515x; 1.0932x over previous
//
#include <hip/hip_runtime.h>
#include <hip/hip_bf16.h>
#include <math.h>

#define B_ 32
#define T_ 4096
#define D_ 512
#define U_ 512

typedef __bf16 bf16x8 __attribute__((ext_vector_type(8)));
typedef float floatx4 __attribute__((ext_vector_type(4)));
typedef unsigned short ushortx8 __attribute__((ext_vector_type(8)));

// exact RNE float -> bf16 (as uint)
static __device__ __forceinline__ unsigned int f2bf(float f) {
  unsigned int u = __float_as_uint(f);
  return (u + 0x7fffu + ((u >> 16) & 1u)) >> 16;
}

// fast tanh: 1 - 2/(exp2(2x*log2e)+1). v_exp_f32 + v_rcp_f32; exact at +/-inf.
static __device__ __forceinline__ float tanh_fast(float x) {
  float e = exp2f(x * 2.88539008178f);
  return 1.0f - 2.0f * __builtin_amdgcn_rcpf(1.0f + e);
}

// pack 8 fp32 -> 8 bf16 (RNE) as uint4 (manual packing; no HIP class types)
static __device__ __forceinline__ uint4 pack8(const float4 a, const float4 b) {
  uint4 pk;
  pk.x = f2bf(a.x) | (f2bf(a.y) << 16);
  pk.y = f2bf(a.z) | (f2bf(a.w) << 16);
  pk.z = f2bf(b.x) | (f2bf(b.y) << 16);
  pk.w = f2bf(b.z) | (f2bf(b.w) << 16);
  return pk;
}

// ---------------------------------------------------------------------------
// P0: pack W2 (fp32 [k][u]) into MFMA-fragment-ordered bf16:
//   W2B[((ub*16 + kb)*64 + lane)*8 + j] = bf16(W2[(kb*32 + (lane>>4)*8 + j)][ub*16 + (lane&15)])
// so a wave's B-fragment load is 64 lanes x 16 B = 1 KB contiguous.
// 32768 slots of 8 shorts; grid 128 x 256.
// ---------------------------------------------------------------------------
__global__ __launch_bounds__(256) void prep_w2b(
    const float* __restrict__ W2, unsigned short* __restrict__ W2B) {
  const int s = blockIdx.x * 256 + threadIdx.x;  // slot id
  const int lane = s & 63;
  const int frag = s >> 6;       // 0..511
  const int ub = frag >> 4;      // u-block of 16
  const int kb = frag & 15;      // k-block of 32
  const int lr = lane & 15;
  const int kc = lane >> 4;
  const int u = ub * 16 + lr;
  const int k0 = kb * 32 + kc * 8;
  ushortx8 pk;
#pragma unroll
  for (int j = 0; j < 8; ++j)
    pk[j] = (unsigned short)f2bf(W2[(size_t)(k0 + j) * U_ + u]);
  *(ushortx8*)&W2B[(size_t)s * 8] = pk;
}

// ---------------------------------------------------------------------------
// K1: q_proj[b][u] = query[b]@W1[:,u] + b1[u] + b2[u]   (fp32, tiny)
// ---------------------------------------------------------------------------
__global__ __launch_bounds__(256) void qproj_kernel(
    const float* __restrict__ query, const float* __restrict__ W1,
    const float* __restrict__ b1, const float* __restrict__ b2,
    float* __restrict__ qp) {
  const int b = blockIdx.x;
  const int tid = threadIdx.x;
  __shared__ float qs[D_];
  qs[tid] = query[b * D_ + tid];
  qs[tid + 256] = query[b * D_ + tid + 256];
  __syncthreads();
  const int u0 = tid * 2;
  float ax = 0.f, ay = 0.f;
#pragma unroll 8
  for (int k = 0; k < D_; ++k) {
    const float q = qs[k];
    const float2 w = *(const float2*)&W1[(size_t)k * U_ + u0];
    ax += q * w.x;
    ay += q * w.y;
  }
  qp[b * U_ + u0] = ax + b1[u0] + b2[u0];
  qp[b * U_ + u0 + 1] = ay + b1[u0 + 1] + b2[u0 + 1];
}

// ---------------------------------------------------------------------------
// K2: scores. Block = 64t x 512u, 4 waves split u. Full-K A tile staged ONCE
// into 64 KB LDS (rotation swizzle, conflict-free), single barrier, then a
// 16-step K-loop with NO barriers: 8 fully-coalesced 1-KB B-fragment loads
// (fragment-packed W2B, L2-resident) + 4 ds_read_b128 + 32 MFMA per step.
// Epilogue: tanh/V dot + shuffle + cross-wave reduce (LDS aliased onto As).
// grid (T/64, B) = (64, 32). values fetched exactly once.
// ---------------------------------------------------------------------------
__global__ __launch_bounds__(256, 2) void scores_mfma(
    const float* __restrict__ values, const unsigned short* __restrict__ W2B,
    const float* __restrict__ qp, const float* __restrict__ V,
    float* __restrict__ scores) {
  const int b = blockIdx.y;
  const int t0 = blockIdx.x * 64;
  const int tid = threadIdx.x;
  const int w = tid >> 6;
  const int lane = tid & 63;
  const int lr = lane & 15;   // fragment row within 16
  const int kc = lane >> 4;   // k-chunk 0..3 (8 shorts each)

  // A tile: 64 rows x 512 k, bf16, rotation-swizzled chunks: row r, chunk k8
  // stored at chunk index (k8 + 4r) & 63. Exactly 64 KB.
  __shared__ __align__(16) unsigned short As[64 * 512];

  const float* vbase = values + ((size_t)b * T_ + t0) * D_;

  // ---- stage full-K A tile (coalesced; one 2-KB row per wave per step) ----
#pragma unroll
  for (int p = 0; p < 16; ++p) {
    const int m = p * 256 + tid;
    const int r = m >> 6;        // row 0..63 (wave-uniform)
    const int k8 = m & 63;       // 16-B chunk within row
    const float4 f0 = *(const float4*)&vbase[(size_t)r * D_ + k8 * 8];
    const float4 f1 = *(const float4*)&vbase[(size_t)r * D_ + k8 * 8 + 4];
    const int c = (k8 + r * 4) & 63;
    *(uint4*)&As[r * 512 + c * 8] = pack8(f0, f1);
  }
  __syncthreads();

  floatx4 acc[4][8];
#pragma unroll
  for (int i = 0; i < 4; ++i)
#pragma unroll
    for (int j = 0; j < 8; ++j) acc[i][j] = (floatx4)0.f;

  const ushortx8* W2Bv = (const ushortx8*)W2B;

  // ---- K loop: no barriers, fully pipelineable ----
#pragma unroll 4
  for (int ks = 0; ks < 16; ++ks) {
    bf16x8 bfr[8];
#pragma unroll
    for (int j = 0; j < 8; ++j)
      bfr[j] = __builtin_bit_cast(
          bf16x8, W2Bv[((w * 8 + j) * 16 + ks) * 64 + lane]);
    bf16x8 af[4];
#pragma unroll
    for (int i = 0; i < 4; ++i) {
      const int ri = i * 16 + lr;
      const int c = (ks * 4 + kc + ri * 4) & 63;
      af[i] = __builtin_bit_cast(bf16x8, *(ushortx8*)&As[ri * 512 + c * 8]);
    }
#pragma unroll
    for (int i = 0; i < 4; ++i)
#pragma unroll
      for (int j = 0; j < 8; ++j)
        acc[i][j] = __builtin_amdgcn_mfma_f32_16x16x32_bf16(af[i], bfr[j],
                                                            acc[i][j], 0, 0, 0);
  }

  // ---- epilogue: C/D layout n(u) = lr, m(t) = i*16 + (lane>>4)*4 + reg ----
  const int no = w * 128;
  const float* qpb = qp + b * U_;
  float qv[8], vv[8];
#pragma unroll
  for (int j = 0; j < 8; ++j) {
    const int u = no + j * 16 + lr;
    qv[j] = qpb[u];
    vv[j] = V[u];
  }
  __syncthreads();                 // all As reads done; safe to alias red
  float* red = (float*)As;         // 4*64 floats
  const int mrow = (lane >> 4) * 4;
#pragma unroll
  for (int i = 0; i < 4; ++i) {
#pragma unroll
    for (int r = 0; r < 4; ++r) {
      float s = 0.f;
#pragma unroll
      for (int j = 0; j < 8; ++j) s += tanh_fast(acc[i][j][r] + qv[j]) * vv[j];
      s += __shfl_xor(s, 1);
      s += __shfl_xor(s, 2);
      s += __shfl_xor(s, 4);
      s += __shfl_xor(s, 8);
      if (lr == 0) red[w * 64 + i * 16 + mrow + r] = s;
    }
  }
  __syncthreads();
  if (tid < 64)
    scores[(size_t)b * T_ + t0 + tid] =
        red[tid] + red[64 + tid] + red[128 + tid] + red[192 + tid];
}

// ---------------------------------------------------------------------------
// K3: softmax over T per batch, in place. grid: 32 blocks x 256 thr.
// ---------------------------------------------------------------------------
__global__ __launch_bounds__(256) void softmax_kernel(float* __restrict__ sc) {
  const int b = blockIdx.x;
  const int tid = threadIdx.x;
  __shared__ float red[256];
  float* s = sc + (size_t)b * T_;
  float v[16];
  float lmax = -1e30f;
#pragma unroll
  for (int i = 0; i < 16; ++i) {
    v[i] = s[tid + 256 * i];
    lmax = fmaxf(lmax, v[i]);
  }
  red[tid] = lmax;
  __syncthreads();
  for (int off = 128; off > 0; off >>= 1) {
    if (tid < off) red[tid] = fmaxf(red[tid], red[tid + off]);
    __syncthreads();
  }
  const float m = red[0];
  __syncthreads();
  float lsum = 0.f;
#pragma unroll
  for (int i = 0; i < 16; ++i) {
    v[i] = expf(v[i] - m);
    lsum += v[i];
  }
  red[tid] = lsum;
  __syncthreads();
  for (int off = 128; off > 0; off >>= 1) {
    if (tid < off) red[tid] += red[tid + off];
    __syncthreads();
  }
  const float inv = 1.0f / red[0];
#pragma unroll
  for (int i = 0; i < 16; ++i) s[tid + 256 * i] = v[i] * inv;
}

// ---------------------------------------------------------------------------
// K4: context[b][d] = sum_t attn[b][t]*values[b][t][d]
// grid (B, 32): 128 t-rows per block; 256 thr = 2 rows x 128 float4 lanes.
// ---------------------------------------------------------------------------
__global__ __launch_bounds__(256) void context_kernel(
    const float* __restrict__ values, const float* __restrict__ attn,
    float* __restrict__ out) {
  const int b = blockIdx.x;
  const int t0 = blockIdx.y * 128;
  const int tid = threadIdx.x;
  const int tx = tid & 127;
  const int ty = tid >> 7;
  __shared__ float as[128];
  __shared__ float4 red[128];
  if (tid < 128) as[tid] = attn[(size_t)b * T_ + t0 + tid];
  __syncthreads();
  const float* vb = values + ((size_t)b * T_ + t0) * D_;
  float ax = 0.f, ay = 0.f, az = 0.f, aw = 0.f;
#pragma unroll 8
  for (int t = ty; t < 128; t += 2) {
    const float a = as[t];
    const float4 v = *(const float4*)&vb[(size_t)t * D_ + tx * 4];
    ax += a * v.x;
    ay += a * v.y;
    az += a * v.z;
    aw += a * v.w;
  }
  if (ty == 1) red[tx] = make_float4(ax, ay, az, aw);
  __syncthreads();
  if (ty == 0) {
    const float4 o = red[tx];
    const int d = tx * 4;
    atomicAdd(&out[b * D_ + d],     ax + o.x);
    atomicAdd(&out[b * D_ + d + 1], ay + o.y);
    atomicAdd(&out[b * D_ + d + 2], az + o.z);
    atomicAdd(&out[b * D_ + d + 3], aw + o.w);
  }
}

// ---------------------------------------------------------------------------
extern "C" void kernel_launch(void* const* d_in, const int* in_sizes, int n_in,
                              void* d_out, int out_size, void* d_ws,
                              size_t ws_size, hipStream_t stream) {
  const float* query = (const float*)d_in[0];
  const float* values = (const float*)d_in[1];
  const float* W1 = (const float*)d_in[2];
  const float* b1 = (const float*)d_in[3];
  const float* W2 = (const float*)d_in[4];
  const float* b2 = (const float*)d_in[5];
  const float* V = (const float*)d_in[6];
  // d_in[7] = bv : dropped (softmax shift-invariant)

  // ws layout: qp (64 KB) | scores (512 KB) | W2B bf16 packed (512 KB)
  float* qp = (float*)d_ws;
  float* scores = qp + (size_t)B_ * U_;
  unsigned short* W2B = (unsigned short*)(scores + (size_t)B_ * T_);
  float* out = (float*)d_out;

  (void)hipMemsetAsync(d_out, 0, (size_t)B_ * D_ * sizeof(float), stream);

  prep_w2b<<<128, 256, 0, stream>>>(W2, W2B);
  qproj_kernel<<<B_, 256, 0, stream>>>(query, W1, b1, b2, qp);
  scores_mfma<<<dim3(T_ / 64, B_), 256, 0, stream>>>(values, W2B, qp, V,
                                                     scores);
  softmax_kernel<<<B_, 256, 0, stream>>>(scores);
  context_kernel<<<dim3(B_, 32), 256, 0, stream>>>(values, scores, out);
}